// Round 3
// baseline (495.716 us; speedup 1.0000x reference)
//
#include <hip/hip_runtime.h>

// Fused MHA: qkv[4,2048,1024] f32 -> out f32, all GEMMs in bf16 MFMA.
// R3: flash — V fragments loaded direct from global (no sV LDS), K tile
// double-buffered with ONE barrier per kv-iter (DMA overlaps full compute
// phase). LDS 40KB = 4 blocks/CU. S^T = K·Q^T, fixed-max exp2 softmax.

typedef __bf16 bf16;
typedef __bf16 bf16x4 __attribute__((ext_vector_type(4)));
typedef __bf16 bf16x8 __attribute__((ext_vector_type(8)));
typedef float f32x4 __attribute__((ext_vector_type(4)));

typedef const __attribute__((address_space(1))) void* gas1p;
typedef __attribute__((address_space(3))) void* las3p;
#define GLD16(g, l) __builtin_amdgcn_global_load_lds((gas1p)(g), (las3p)(l), 16, 0, 0)

#if __has_builtin(__builtin_amdgcn_exp2f)
#define EXP2(x) __builtin_amdgcn_exp2f(x)
#else
#define EXP2(x) exp2f(x)
#endif

__device__ __forceinline__ f32x4 mfma16(bf16x8 a, bf16x8 b, f32x4 c) {
  return __builtin_amdgcn_mfma_f32_16x16x32_bf16(a, b, c, 0, 0, 0);
}

// ---------------- elementwise cast f32 -> bf16 ----------------
__global__ void cast_kernel(const float* __restrict__ in, bf16* __restrict__ out, int n) {
  int i = (blockIdx.x * 256 + threadIdx.x) * 4;
  if (i < n) {
    float4 v = *(const float4*)(in + i);
    bf16x4 o;
    o[0] = (bf16)v.x; o[1] = (bf16)v.y; o[2] = (bf16)v.z; o[3] = (bf16)v.w;
    *(bf16x4*)(out + i) = o;
  }
}

// ---------------- tiled transpose + cast: in[R][C] f32 -> out[C][R] bf16 ----------------
__global__ void transpose_cast_kernel(const float* __restrict__ in, bf16* __restrict__ out,
                                      int R, int C) {
  __shared__ float tile[32][33];
  int c0 = blockIdx.x * 32, r0 = blockIdx.y * 32;
  int tx = threadIdx.x, ty = threadIdx.y;
#pragma unroll
  for (int i = 0; i < 4; ++i)
    tile[ty + i * 8][tx] = in[(size_t)(r0 + ty + i * 8) * C + c0 + tx];
  __syncthreads();
#pragma unroll
  for (int i = 0; i < 4; ++i)
    out[(size_t)(c0 + ty + i * 8) * R + r0 + tx] = (bf16)tile[tx][ty + i * 8];
}

// ---------------- GEMM1: A[8192,1024] @ Bt[3072,1024]^T + bias -> Q,K,Vt (bf16) ----------------
__global__ __launch_bounds__(256, 2) void gemm1_kernel(
    const bf16* __restrict__ A, const bf16* __restrict__ Bt, const float* __restrict__ bias,
    bf16* __restrict__ Qo, bf16* __restrict__ Ko, bf16* __restrict__ Vo) {
  __shared__ __align__(16) char sA[128 * 64 * 2];
  __shared__ __align__(16) char sB[128 * 64 * 2];
  const int tid = threadIdx.x, lane = tid & 63, wave = tid >> 6, quad = lane >> 4;
  const int m0 = blockIdx.y * 128, n0 = blockIdx.x * 128;
  const int wm = (wave >> 1) * 64, wn = (wave & 1) * 64;
  f32x4 acc[4][4] = {};

  for (int kt = 0; kt < 1024; kt += 64) {
    __syncthreads();
#pragma unroll
    for (int i = 0; i < 4; ++i) {
      int chunk = i * 256 + tid;
      int row = chunk >> 3;
      int cs = (chunk & 7) ^ (row & 7);
      GLD16(A + (size_t)(m0 + row) * 1024 + kt + cs * 8, sA + chunk * 16);
      GLD16(Bt + (size_t)(n0 + row) * 1024 + kt + cs * 8, sB + chunk * 16);
    }
    __syncthreads();
#pragma unroll
    for (int ks = 0; ks < 2; ++ks) {
      bf16x8 af[4], bfr[4];
#pragma unroll
      for (int t = 0; t < 4; ++t) {
        int ra = wm + t * 16 + (lane & 15);
        af[t] = *(const bf16x8*)(sA + ra * 128 + ((ks * 4 + quad) ^ (ra & 7)) * 16);
        int rb = wn + t * 16 + (lane & 15);
        bfr[t] = *(const bf16x8*)(sB + rb * 128 + ((ks * 4 + quad) ^ (rb & 7)) * 16);
      }
#pragma unroll
      for (int mt = 0; mt < 4; ++mt)
#pragma unroll
        for (int nt = 0; nt < 4; ++nt)
          acc[mt][nt] = mfma16(af[mt], bfr[nt], acc[mt][nt]);
    }
  }

  const int region = n0 >> 10;  // 0=Q, 1=K, 2=V
#pragma unroll
  for (int nt = 0; nt < 4; ++nt) {
    int n = n0 + wn + nt * 16 + (lane & 15);
    float bv = bias[n];
    int ncol = n & 1023;
    int h = ncol >> 6, d = ncol & 63;
#pragma unroll
    for (int mt = 0; mt < 4; ++mt) {
      int gm = m0 + wm + mt * 16 + quad * 4;
      int bb = gm >> 11, s = gm & 2047;
      if (region == 2) {
        bf16x4 pk;
#pragma unroll
        for (int r = 0; r < 4; ++r) pk[r] = (bf16)(acc[mt][nt][r] + bv);
        *(bf16x4*)(Vo + ((size_t)((bb * 16 + h) * 64 + d)) * 2048 + s) = pk;
      } else {
        bf16* dst = (region == 0) ? Qo : Ko;
        // Q scale: 1/sqrt(64) * log2(e)  (softmax done in base-2)
        float scl = (region == 0) ? 0.18033688f : 1.0f;
#pragma unroll
        for (int r = 0; r < 4; ++r)
          dst[((size_t)((bb * 16 + h) * 2048) + s + r) * 64 + d] =
              (bf16)((acc[mt][nt][r] + bv) * scl);
      }
    }
  }
}

// ---------------- flash attention v3 ----------------
// grid 1024, 256 threads (4 waves x 32 q-rows). S^T = K Q^T; V direct from
// global; K double-buffered, one barrier per iter.
__global__ __launch_bounds__(256, 4) void flash_kernel(
    const bf16* __restrict__ Q, const bf16* __restrict__ K, const bf16* __restrict__ Vt,
    bf16* __restrict__ ctx) {
  const int n = blockIdx.x;
  const int bh = (n & 7) * 8 + (n >> 7);   // XCD swizzle: 8 heads share an XCD L2
  const int qt = (n >> 3) & 15;
  const int b = bh >> 4, h = bh & 15;
  const int tid = threadIdx.x, lane = tid & 63, wave = tid >> 6, quad = lane >> 4;

  __shared__ __align__(16) char sK[2][128 * 64 * 2];  // K dbuf, 2x16KB
  __shared__ __align__(16) char sP[4][32 * 32 * 2];   // per-wave [32q][32kv] 8KB

  const size_t hb = (size_t)bh * 2048 * 64;
  const int q0 = qt * 128;

  // stage Q -> buf1, K tile 0 -> buf0
#pragma unroll
  for (int i = 0; i < 4; ++i) {
    int chunk = i * 256 + tid;
    int row = chunk >> 3;
    int cs = (chunk & 7) ^ (row & 7);
    GLD16(Q + hb + (size_t)(q0 + row) * 64 + cs * 8, sK[1] + chunk * 16);
    GLD16(K + hb + (size_t)row * 64 + cs * 8, sK[0] + chunk * 16);
  }
  __syncthreads();
  bf16x8 qf[2][2];  // [j: q 16-tile][ksd: d-half]
#pragma unroll
  for (int j = 0; j < 2; ++j)
#pragma unroll
    for (int ksd = 0; ksd < 2; ++ksd) {
      int row = wave * 32 + j * 16 + (lane & 15);
      qf[j][ksd] = *(const bf16x8*)(sK[1] + row * 128 + ((ksd * 4 + quad) ^ (row & 7)) * 16);
    }
  __syncthreads();  // all waves done reading Q before buf1 is re-staged

  // per-lane V base: Vt[bh][d = lane&15 (+16*nd)][kv = quad*8 (+kq*32 + kv0)]
  const bf16* vbase = Vt + hb + (size_t)(lane & 15) * 2048 + quad * 8;

  f32x4 ctxa[2][4] = {};
  float l[2] = {0.f, 0.f};
  char* pw = sP[wave];

  for (int it = 0; it < 16; ++it) {
    const int kv0 = it * 128;
    // prefetch next K tile into the other buffer; overlaps with all compute below
    if (it < 15) {
      char* nb = sK[(it + 1) & 1];
#pragma unroll
      for (int i = 0; i < 4; ++i) {
        int chunk = i * 256 + tid;
        int row = chunk >> 3;
        int cs = (chunk & 7) ^ (row & 7);
        GLD16(K + hb + (size_t)(kv0 + 128 + row) * 64 + cs * 8, nb + chunk * 16);
      }
    }
    const char* cb = sK[it & 1];

    // kv quarters of 32
#pragma unroll
    for (int kq = 0; kq < 4; ++kq) {
      // V fragments for this quarter, straight from global (L2-resident)
      bf16x8 vf[4];
#pragma unroll
      for (int nd = 0; nd < 4; ++nd)
        vf[nd] = *(const bf16x8*)(vbase + (size_t)nd * 32768 + kv0 + kq * 32);

      // S^T tile: [2 kv-16-tiles][2 q-16-tiles]
      f32x4 st[2][2] = {};
#pragma unroll
      for (int ksd = 0; ksd < 2; ++ksd) {
        bf16x8 kf[2];
#pragma unroll
        for (int ii = 0; ii < 2; ++ii) {
          int row = kq * 32 + ii * 16 + (lane & 15);
          kf[ii] = *(const bf16x8*)(cb + row * 128 + ((ksd * 4 + quad) ^ (row & 7)) * 16);
        }
#pragma unroll
        for (int ii = 0; ii < 2; ++ii)
#pragma unroll
          for (int j = 0; j < 2; ++j)
            st[ii][j] = mfma16(kf[ii], qf[j][ksd], st[ii][j]);
      }
      // p = exp2(s); accumulate row-sum in-lane; write P^T quarter (vectorized)
#pragma unroll
      for (int ii = 0; ii < 2; ++ii)
#pragma unroll
        for (int j = 0; j < 2; ++j) {
          f32x4 p;
#pragma unroll
          for (int r = 0; r < 4; ++r) {
            p[r] = EXP2(st[ii][j][r]);
            l[j] += p[r];
          }
          bf16x4 pk;
#pragma unroll
          for (int r = 0; r < 4; ++r) pk[r] = (bf16)p[r];
          int q = j * 16 + (lane & 15);
          int chunk = ii * 2 + (quad >> 1);
          *(bf16x4*)(pw + q * 64 + ((chunk ^ (q & 3)) * 16) + (quad & 1) * 8) = pk;
        }
      // ctx += P @ V  (quarter: k = 32 kv)
      bf16x8 pf[2];
#pragma unroll
      for (int mt = 0; mt < 2; ++mt) {
        int q = mt * 16 + (lane & 15);
        pf[mt] = *(const bf16x8*)(pw + q * 64 + ((quad ^ (q & 3)) * 16));
      }
#pragma unroll
      for (int mt = 0; mt < 2; ++mt)
#pragma unroll
        for (int nd = 0; nd < 4; ++nd)
          ctxa[mt][nd] = mfma16(pf[mt], vf[nd], ctxa[mt][nd]);
    }
    __syncthreads();  // drains next-tile DMA (overlapped) + fences buf reads
  }

  // final cross-quad row-sum reduction, then epilogue
#pragma unroll
  for (int j = 0; j < 2; ++j) {
    l[j] += __shfl_xor(l[j], 16);
    l[j] += __shfl_xor(l[j], 32);
  }
#pragma unroll
  for (int mt = 0; mt < 2; ++mt)
#pragma unroll
    for (int r = 0; r < 4; ++r) {
      float lsh = __shfl(l[mt], quad * 4 + r);
      float rl = __builtin_amdgcn_rcpf(lsh);
      int srow = q0 + wave * 32 + mt * 16 + quad * 4 + r;
#pragma unroll
      for (int nd = 0; nd < 4; ++nd) {
        int col = h * 64 + nd * 16 + (lane & 15);
        ctx[((size_t)(b * 2048 + srow)) * 1024 + col] = (bf16)(ctxa[mt][nd][r] * rl);
      }
    }
}

// ---------------- GEMM2: ctx[8192,1024] @ Bt[1024,1024]^T + b_out -> f32 out ----------------
__global__ __launch_bounds__(256, 2) void gemm2_kernel(
    const bf16* __restrict__ A, const bf16* __restrict__ Bt, const float* __restrict__ bias,
    float* __restrict__ Out) {
  __shared__ __align__(16) char sA[128 * 64 * 2];
  __shared__ __align__(16) char sB[128 * 64 * 2];
  const int tid = threadIdx.x, lane = tid & 63, wave = tid >> 6, quad = lane >> 4;
  const int m0 = blockIdx.y * 128, n0 = blockIdx.x * 128;
  const int wm = (wave >> 1) * 64, wn = (wave & 1) * 64;
  f32x4 acc[4][4] = {};

  for (int kt = 0; kt < 1024; kt += 64) {
    __syncthreads();
#pragma unroll
    for (int i = 0; i < 4; ++i) {
      int chunk = i * 256 + tid;
      int row = chunk >> 3;
      int cs = (chunk & 7) ^ (row & 7);
      GLD16(A + (size_t)(m0 + row) * 1024 + kt + cs * 8, sA + chunk * 16);
      GLD16(Bt + (size_t)(n0 + row) * 1024 + kt + cs * 8, sB + chunk * 16);
    }
    __syncthreads();
#pragma unroll
    for (int ks = 0; ks < 2; ++ks) {
      bf16x8 af[4], bfr[4];
#pragma unroll
      for (int t = 0; t < 4; ++t) {
        int ra = wm + t * 16 + (lane & 15);
        af[t] = *(const bf16x8*)(sA + ra * 128 + ((ks * 4 + quad) ^ (ra & 7)) * 16);
        int rb = wn + t * 16 + (lane & 15);
        bfr[t] = *(const bf16x8*)(sB + rb * 128 + ((ks * 4 + quad) ^ (rb & 7)) * 16);
      }
#pragma unroll
      for (int mt = 0; mt < 4; ++mt)
#pragma unroll
        for (int nt = 0; nt < 4; ++nt)
          acc[mt][nt] = mfma16(af[mt], bfr[nt], acc[mt][nt]);
    }
  }

#pragma unroll
  for (int nt = 0; nt < 4; ++nt) {
    int n = n0 + wn + nt * 16 + (lane & 15);
    float bv = bias[n];
#pragma unroll
    for (int mt = 0; mt < 4; ++mt) {
      int gm = m0 + wm + mt * 16 + quad * 4;
#pragma unroll
      for (int r = 0; r < 4; ++r)
        Out[(size_t)(gm + r) * 1024 + n] = acc[mt][nt][r] + bv;
    }
  }
}

extern "C" void kernel_launch(void* const* d_in, const int* in_sizes, int n_in,
                              void* d_out, int out_size, void* d_ws, size_t ws_size,
                              hipStream_t stream) {
  const float* qkv   = (const float*)d_in[0];
  const float* W_in  = (const float*)d_in[1];
  const float* b_in  = (const float*)d_in[2];
  const float* W_out = (const float*)d_in[3];
  const float* b_out = (const float*)d_in[4];
  float* out = (float*)d_out;

  bf16* Xb    = (bf16*)d_ws;
  bf16* WtIn  = Xb + 8388608;
  bf16* WtOut = WtIn + 3145728;
  bf16* Qb    = WtOut + 1048576;
  bf16* Kb    = Qb + 8388608;
  bf16* Vtb   = Kb + 8388608;
  bf16* Ctx   = Xb;

  cast_kernel<<<8192, 256, 0, stream>>>(qkv, Xb, 8388608);
  transpose_cast_kernel<<<dim3(96, 32), dim3(32, 8), 0, stream>>>(W_in, WtIn, 1024, 3072);
  transpose_cast_kernel<<<dim3(32, 32), dim3(32, 8), 0, stream>>>(W_out, WtOut, 1024, 1024);
  gemm1_kernel<<<dim3(24, 64), 256, 0, stream>>>(Xb, WtIn, b_in, Qb, Kb, Vtb);
  flash_kernel<<<1024, 256, 0, stream>>>(Qb, Kb, Vtb, Ctx);
  gemm2_kernel<<<dim3(8, 64), 256, 0, stream>>>(Ctx, WtOut, b_out, out);
}

// Round 4
// 265.239 us; speedup vs baseline: 1.8689x; 1.8689x over previous
//
#include <hip/hip_runtime.h>

// Fused MHA: qkv[4,2048,1024] f32 -> out f32, all GEMMs in bf16 MFMA.
// R4: flash — 256 q-rows/block (64/wave), K AND V double-buffered in LDS,
// ONE barrier per 128-kv iter (DMA drains after full compute phase).
// LDS 80KB = 2 blocks/CU, grid 512. S^T = K·Q^T, fixed-max exp2 softmax.
// (R3 lesson: V direct-from-global thrashes L2 — 471MB HBM fetch. Stage V.)

typedef __bf16 bf16;
typedef __bf16 bf16x4 __attribute__((ext_vector_type(4)));
typedef __bf16 bf16x8 __attribute__((ext_vector_type(8)));
typedef float f32x4 __attribute__((ext_vector_type(4)));

typedef const __attribute__((address_space(1))) void* gas1p;
typedef __attribute__((address_space(3))) void* las3p;
#define GLD16(g, l) __builtin_amdgcn_global_load_lds((gas1p)(g), (las3p)(l), 16, 0, 0)

#if __has_builtin(__builtin_amdgcn_exp2f)
#define EXP2(x) __builtin_amdgcn_exp2f(x)
#else
#define EXP2(x) exp2f(x)
#endif

__device__ __forceinline__ f32x4 mfma16(bf16x8 a, bf16x8 b, f32x4 c) {
  return __builtin_amdgcn_mfma_f32_16x16x32_bf16(a, b, c, 0, 0, 0);
}

// ---------------- elementwise cast f32 -> bf16 ----------------
__global__ void cast_kernel(const float* __restrict__ in, bf16* __restrict__ out, int n) {
  int i = (blockIdx.x * 256 + threadIdx.x) * 4;
  if (i < n) {
    float4 v = *(const float4*)(in + i);
    bf16x4 o;
    o[0] = (bf16)v.x; o[1] = (bf16)v.y; o[2] = (bf16)v.z; o[3] = (bf16)v.w;
    *(bf16x4*)(out + i) = o;
  }
}

// ---------------- tiled transpose + cast: in[R][C] f32 -> out[C][R] bf16 ----------------
__global__ void transpose_cast_kernel(const float* __restrict__ in, bf16* __restrict__ out,
                                      int R, int C) {
  __shared__ float tile[32][33];
  int c0 = blockIdx.x * 32, r0 = blockIdx.y * 32;
  int tx = threadIdx.x, ty = threadIdx.y;
#pragma unroll
  for (int i = 0; i < 4; ++i)
    tile[ty + i * 8][tx] = in[(size_t)(r0 + ty + i * 8) * C + c0 + tx];
  __syncthreads();
#pragma unroll
  for (int i = 0; i < 4; ++i)
    out[(size_t)(c0 + ty + i * 8) * R + r0 + tx] = (bf16)tile[tx][ty + i * 8];
}

// ---------------- GEMM1: A[8192,1024] @ Bt[3072,1024]^T + bias -> Q,K,Vt (bf16) ----------------
__global__ __launch_bounds__(256, 2) void gemm1_kernel(
    const bf16* __restrict__ A, const bf16* __restrict__ Bt, const float* __restrict__ bias,
    bf16* __restrict__ Qo, bf16* __restrict__ Ko, bf16* __restrict__ Vo) {
  __shared__ __align__(16) char sA[128 * 64 * 2];
  __shared__ __align__(16) char sB[128 * 64 * 2];
  const int tid = threadIdx.x, lane = tid & 63, wave = tid >> 6, quad = lane >> 4;
  const int m0 = blockIdx.y * 128, n0 = blockIdx.x * 128;
  const int wm = (wave >> 1) * 64, wn = (wave & 1) * 64;
  f32x4 acc[4][4] = {};

  for (int kt = 0; kt < 1024; kt += 64) {
    __syncthreads();
#pragma unroll
    for (int i = 0; i < 4; ++i) {
      int chunk = i * 256 + tid;
      int row = chunk >> 3;
      int cs = (chunk & 7) ^ (row & 7);
      GLD16(A + (size_t)(m0 + row) * 1024 + kt + cs * 8, sA + chunk * 16);
      GLD16(Bt + (size_t)(n0 + row) * 1024 + kt + cs * 8, sB + chunk * 16);
    }
    __syncthreads();
#pragma unroll
    for (int ks = 0; ks < 2; ++ks) {
      bf16x8 af[4], bfr[4];
#pragma unroll
      for (int t = 0; t < 4; ++t) {
        int ra = wm + t * 16 + (lane & 15);
        af[t] = *(const bf16x8*)(sA + ra * 128 + ((ks * 4 + quad) ^ (ra & 7)) * 16);
        int rb = wn + t * 16 + (lane & 15);
        bfr[t] = *(const bf16x8*)(sB + rb * 128 + ((ks * 4 + quad) ^ (rb & 7)) * 16);
      }
#pragma unroll
      for (int mt = 0; mt < 4; ++mt)
#pragma unroll
        for (int nt = 0; nt < 4; ++nt)
          acc[mt][nt] = mfma16(af[mt], bfr[nt], acc[mt][nt]);
    }
  }

  const int region = n0 >> 10;  // 0=Q, 1=K, 2=V
#pragma unroll
  for (int nt = 0; nt < 4; ++nt) {
    int n = n0 + wn + nt * 16 + (lane & 15);
    float bv = bias[n];
    int ncol = n & 1023;
    int h = ncol >> 6, d = ncol & 63;
#pragma unroll
    for (int mt = 0; mt < 4; ++mt) {
      int gm = m0 + wm + mt * 16 + quad * 4;
      int bb = gm >> 11, s = gm & 2047;
      if (region == 2) {
        bf16x4 pk;
#pragma unroll
        for (int r = 0; r < 4; ++r) pk[r] = (bf16)(acc[mt][nt][r] + bv);
        *(bf16x4*)(Vo + ((size_t)((bb * 16 + h) * 64 + d)) * 2048 + s) = pk;
      } else {
        bf16* dst = (region == 0) ? Qo : Ko;
        // Q scale: 1/sqrt(64) * log2(e)  (softmax done in base-2)
        float scl = (region == 0) ? 0.18033688f : 1.0f;
#pragma unroll
        for (int r = 0; r < 4; ++r)
          dst[((size_t)((bb * 16 + h) * 2048) + s + r) * 64 + d] =
              (bf16)((acc[mt][nt][r] + bv) * scl);
      }
    }
  }
}

// ---------------- flash attention v4 ----------------
// grid 512, 256 threads (4 waves x 64 q-rows = 256 q/block).
// S^T = K Q^T; K,V double-buffered in LDS; one barrier per 128-kv iter.
__global__ __launch_bounds__(256, 2) void flash_kernel(
    const bf16* __restrict__ Q, const bf16* __restrict__ K, const bf16* __restrict__ Vt,
    bf16* __restrict__ ctx) {
  const int n = blockIdx.x;
  const int bh = (n & 7) * 8 + (n >> 6);   // XCD swizzle: 8 heads share an XCD L2
  const int qt = (n >> 3) & 7;
  const int b = bh >> 4, h = bh & 15;
  const int tid = threadIdx.x, lane = tid & 63, wave = tid >> 6, quad = lane >> 4;

  __shared__ __align__(16) char sK[2][128 * 64 * 2];  // K dbuf, 2x16KB
  __shared__ __align__(16) char sV[2][64 * 128 * 2];  // V dbuf [d][kv], 2x16KB
  __shared__ __align__(16) char sP[4][64 * 32 * 2];   // per-wave [64q][32kv] 4KB

  const size_t hb = (size_t)bh * 2048 * 64;
  const int q0 = qt * 256;

  // stage Q tile (256 rows) into sK[0]+sK[1] (borrowed), preload qf fragments
#pragma unroll
  for (int i = 0; i < 8; ++i) {
    int chunk = i * 256 + tid;
    int row = chunk >> 3;
    int cs = (chunk & 7) ^ (row & 7);
    char* dst = (i < 4) ? (sK[0] + chunk * 16) : (sK[1] + (chunk - 1024) * 16);
    GLD16(Q + hb + (size_t)(q0 + row) * 64 + cs * 8, dst);
  }
  __syncthreads();
  bf16x8 qf[4][2];  // [j: q 16-tile][ksd: d-half]
#pragma unroll
  for (int j = 0; j < 4; ++j)
#pragma unroll
    for (int ksd = 0; ksd < 2; ++ksd) {
      int row = wave * 64 + j * 16 + (lane & 15);  // 0..255
      const char* src = sK[row >> 7];
      int r128 = row & 127;
      qf[j][ksd] = *(const bf16x8*)(src + r128 * 128 + ((ksd * 4 + quad) ^ (r128 & 7)) * 16);
    }
  __syncthreads();  // all waves done reading Q before buffers are re-staged

  // prologue DMA: K tile 0 -> sK[0], V tile 0 -> sV[0]
#pragma unroll
  for (int i = 0; i < 4; ++i) {
    int chunk = i * 256 + tid;
    int row = chunk >> 3;
    int cs = (chunk & 7) ^ (row & 7);
    GLD16(K + hb + (size_t)row * 64 + cs * 8, sK[0] + chunk * 16);
    int vrow = chunk >> 4;
    int vcs = (chunk & 15) ^ (vrow & 7);
    GLD16(Vt + hb + (size_t)vrow * 2048 + vcs * 8, sV[0] + chunk * 16);
  }
  __syncthreads();

  f32x4 ctxa[4][4] = {};
  float l[4] = {0.f, 0.f, 0.f, 0.f};
  char* pw = sP[wave];

  for (int it = 0; it < 16; ++it) {
    const int kv0 = it * 128;
    // prefetch next K/V tiles into the other buffers; overlaps all compute below
    if (it < 15) {
      char* nk = sK[(it + 1) & 1];
      char* nv = sV[(it + 1) & 1];
#pragma unroll
      for (int i = 0; i < 4; ++i) {
        int chunk = i * 256 + tid;
        int row = chunk >> 3;
        int cs = (chunk & 7) ^ (row & 7);
        GLD16(K + hb + (size_t)(kv0 + 128 + row) * 64 + cs * 8, nk + chunk * 16);
        int vrow = chunk >> 4;
        int vcs = (chunk & 15) ^ (vrow & 7);
        GLD16(Vt + hb + (size_t)vrow * 2048 + kv0 + 128 + vcs * 8, nv + chunk * 16);
      }
    }
    const char* cb = sK[it & 1];
    const char* vb = sV[it & 1];

    // kv quarters of 32
#pragma unroll
    for (int kq = 0; kq < 4; ++kq) {
      // S^T tile: [2 kv-16-tiles][4 q-16-tiles]
      f32x4 st[2][4] = {};
#pragma unroll
      for (int ksd = 0; ksd < 2; ++ksd) {
        bf16x8 kf[2];
#pragma unroll
        for (int ii = 0; ii < 2; ++ii) {
          int row = kq * 32 + ii * 16 + (lane & 15);
          kf[ii] = *(const bf16x8*)(cb + row * 128 + ((ksd * 4 + quad) ^ (row & 7)) * 16);
        }
#pragma unroll
        for (int ii = 0; ii < 2; ++ii)
#pragma unroll
          for (int j = 0; j < 4; ++j)
            st[ii][j] = mfma16(kf[ii], qf[j][ksd], st[ii][j]);
      }
      // p = exp2(s); accumulate row-sum in-lane; write P^T quarter (8B stores)
#pragma unroll
      for (int ii = 0; ii < 2; ++ii)
#pragma unroll
        for (int j = 0; j < 4; ++j) {
          f32x4 p;
#pragma unroll
          for (int r = 0; r < 4; ++r) {
            p[r] = EXP2(st[ii][j][r]);
            l[j] += p[r];
          }
          bf16x4 pk;
#pragma unroll
          for (int r = 0; r < 4; ++r) pk[r] = (bf16)p[r];
          int q = j * 16 + (lane & 15);
          int chunk = ii * 2 + (quad >> 1);
          *(bf16x4*)(pw + q * 64 + ((chunk ^ (q & 3)) * 16) + (quad & 1) * 8) = pk;
        }
      // ctx += P @ V  (quarter: k = 32 kv)
      bf16x8 pf[4], vf[4];
#pragma unroll
      for (int mt = 0; mt < 4; ++mt) {
        int q = mt * 16 + (lane & 15);
        pf[mt] = *(const bf16x8*)(pw + q * 64 + ((quad ^ (q & 3)) * 16));
      }
#pragma unroll
      for (int nd = 0; nd < 4; ++nd) {
        int row = nd * 16 + (lane & 15);
        vf[nd] = *(const bf16x8*)(vb + row * 256 + (((kq * 4 + quad) ^ (row & 7)) * 16));
      }
#pragma unroll
      for (int mt = 0; mt < 4; ++mt)
#pragma unroll
        for (int nd = 0; nd < 4; ++nd)
          ctxa[mt][nd] = mfma16(pf[mt], vf[nd], ctxa[mt][nd]);
    }
    __syncthreads();  // fences buf reads; drains next-tile DMA (fully overlapped)
  }

  // final cross-quad row-sum reduction, then epilogue
#pragma unroll
  for (int j = 0; j < 4; ++j) {
    l[j] += __shfl_xor(l[j], 16);
    l[j] += __shfl_xor(l[j], 32);
  }
#pragma unroll
  for (int mt = 0; mt < 4; ++mt)
#pragma unroll
    for (int r = 0; r < 4; ++r) {
      float lsh = __shfl(l[mt], quad * 4 + r);
      float rl = __builtin_amdgcn_rcpf(lsh);
      int srow = q0 + wave * 64 + mt * 16 + quad * 4 + r;
#pragma unroll
      for (int nd = 0; nd < 4; ++nd) {
        int col = h * 64 + nd * 16 + (lane & 15);
        ctx[((size_t)(b * 2048 + srow)) * 1024 + col] = (bf16)(ctxa[mt][nd][r] * rl);
      }
    }
}

// ---------------- GEMM2: ctx[8192,1024] @ Bt[1024,1024]^T + b_out -> f32 out ----------------
__global__ __launch_bounds__(256, 2) void gemm2_kernel(
    const bf16* __restrict__ A, const bf16* __restrict__ Bt, const float* __restrict__ bias,
    float* __restrict__ Out) {
  __shared__ __align__(16) char sA[128 * 64 * 2];
  __shared__ __align__(16) char sB[128 * 64 * 2];
  const int tid = threadIdx.x, lane = tid & 63, wave = tid >> 6, quad = lane >> 4;
  const int m0 = blockIdx.y * 128, n0 = blockIdx.x * 128;
  const int wm = (wave >> 1) * 64, wn = (wave & 1) * 64;
  f32x4 acc[4][4] = {};

  for (int kt = 0; kt < 1024; kt += 64) {
    __syncthreads();
#pragma unroll
    for (int i = 0; i < 4; ++i) {
      int chunk = i * 256 + tid;
      int row = chunk >> 3;
      int cs = (chunk & 7) ^ (row & 7);
      GLD16(A + (size_t)(m0 + row) * 1024 + kt + cs * 8, sA + chunk * 16);
      GLD16(Bt + (size_t)(n0 + row) * 1024 + kt + cs * 8, sB + chunk * 16);
    }
    __syncthreads();
#pragma unroll
    for (int ks = 0; ks < 2; ++ks) {
      bf16x8 af[4], bfr[4];
#pragma unroll
      for (int t = 0; t < 4; ++t) {
        int ra = wm + t * 16 + (lane & 15);
        af[t] = *(const bf16x8*)(sA + ra * 128 + ((ks * 4 + quad) ^ (ra & 7)) * 16);
        int rb = wn + t * 16 + (lane & 15);
        bfr[t] = *(const bf16x8*)(sB + rb * 128 + ((ks * 4 + quad) ^ (rb & 7)) * 16);
      }
#pragma unroll
      for (int mt = 0; mt < 4; ++mt)
#pragma unroll
        for (int nt = 0; nt < 4; ++nt)
          acc[mt][nt] = mfma16(af[mt], bfr[nt], acc[mt][nt]);
    }
  }

#pragma unroll
  for (int nt = 0; nt < 4; ++nt) {
    int n = n0 + wn + nt * 16 + (lane & 15);
    float bv = bias[n];
#pragma unroll
    for (int mt = 0; mt < 4; ++mt) {
      int gm = m0 + wm + mt * 16 + quad * 4;
#pragma unroll
      for (int r = 0; r < 4; ++r)
        Out[(size_t)(gm + r) * 1024 + n] = acc[mt][nt][r] + bv;
    }
  }
}

extern "C" void kernel_launch(void* const* d_in, const int* in_sizes, int n_in,
                              void* d_out, int out_size, void* d_ws, size_t ws_size,
                              hipStream_t stream) {
  const float* qkv   = (const float*)d_in[0];
  const float* W_in  = (const float*)d_in[1];
  const float* b_in  = (const float*)d_in[2];
  const float* W_out = (const float*)d_in[3];
  const float* b_out = (const float*)d_in[4];
  float* out = (float*)d_out;

  bf16* Xb    = (bf16*)d_ws;
  bf16* WtIn  = Xb + 8388608;
  bf16* WtOut = WtIn + 3145728;
  bf16* Qb    = WtOut + 1048576;
  bf16* Kb    = Qb + 8388608;
  bf16* Vtb   = Kb + 8388608;
  bf16* Ctx   = Xb;

  cast_kernel<<<8192, 256, 0, stream>>>(qkv, Xb, 8388608);
  transpose_cast_kernel<<<dim3(96, 32), dim3(32, 8), 0, stream>>>(W_in, WtIn, 1024, 3072);
  transpose_cast_kernel<<<dim3(32, 32), dim3(32, 8), 0, stream>>>(W_out, WtOut, 1024, 1024);
  gemm1_kernel<<<dim3(24, 64), 256, 0, stream>>>(Xb, WtIn, b_in, Qb, Kb, Vtb);
  flash_kernel<<<512, 256, 0, stream>>>(Qb, Kb, Vtb, Ctx);
  gemm2_kernel<<<dim3(8, 64), 256, 0, stream>>>(Ctx, WtOut, b_out, out);
}

// Round 5
// 264.164 us; speedup vs baseline: 1.8765x; 1.0041x over previous
//
#include <hip/hip_runtime.h>

// Fused MHA: qkv[4,2048,1024] f32 -> out f32, all GEMMs in bf16 MFMA.
// R5: gemm1/gemm2 get the R4-proven double-buffered single-barrier K-loop
// (prefetch tile t+1 via global_load_lds before computing tile t; iter-end
// __syncthreads drains DMA after a full compute phase). LDS 64KB = 2 blk/CU.
// Flash v4 unchanged (86.6us, MfmaUtil 32.5%).

typedef __bf16 bf16;
typedef __bf16 bf16x4 __attribute__((ext_vector_type(4)));
typedef __bf16 bf16x8 __attribute__((ext_vector_type(8)));
typedef float f32x4 __attribute__((ext_vector_type(4)));

typedef const __attribute__((address_space(1))) void* gas1p;
typedef __attribute__((address_space(3))) void* las3p;
#define GLD16(g, l) __builtin_amdgcn_global_load_lds((gas1p)(g), (las3p)(l), 16, 0, 0)

#if __has_builtin(__builtin_amdgcn_exp2f)
#define EXP2(x) __builtin_amdgcn_exp2f(x)
#else
#define EXP2(x) exp2f(x)
#endif

__device__ __forceinline__ f32x4 mfma16(bf16x8 a, bf16x8 b, f32x4 c) {
  return __builtin_amdgcn_mfma_f32_16x16x32_bf16(a, b, c, 0, 0, 0);
}

// ---------------- elementwise cast f32 -> bf16 ----------------
__global__ void cast_kernel(const float* __restrict__ in, bf16* __restrict__ out, int n) {
  int i = (blockIdx.x * 256 + threadIdx.x) * 4;
  if (i < n) {
    float4 v = *(const float4*)(in + i);
    bf16x4 o;
    o[0] = (bf16)v.x; o[1] = (bf16)v.y; o[2] = (bf16)v.z; o[3] = (bf16)v.w;
    *(bf16x4*)(out + i) = o;
  }
}

// ---------------- tiled transpose + cast: in[R][C] f32 -> out[C][R] bf16 ----------------
__global__ void transpose_cast_kernel(const float* __restrict__ in, bf16* __restrict__ out,
                                      int R, int C) {
  __shared__ float tile[32][33];
  int c0 = blockIdx.x * 32, r0 = blockIdx.y * 32;
  int tx = threadIdx.x, ty = threadIdx.y;
#pragma unroll
  for (int i = 0; i < 4; ++i)
    tile[ty + i * 8][tx] = in[(size_t)(r0 + ty + i * 8) * C + c0 + tx];
  __syncthreads();
#pragma unroll
  for (int i = 0; i < 4; ++i)
    out[(size_t)(c0 + ty + i * 8) * R + r0 + tx] = (bf16)tile[tx][ty + i * 8];
}

// ======== shared dbuf-GEMM machinery: 128x128 tile, BK=64, K=1024 ========
// stage one 128x64 bf16 tile (A row-major K-contig) into LDS with XOR swizzle
__device__ __forceinline__ void stage_tile(const bf16* __restrict__ src, size_t rstride,
                                           int kt, char* dst, int tid) {
#pragma unroll
  for (int i = 0; i < 4; ++i) {
    int chunk = i * 256 + tid;
    int row = chunk >> 3;
    int cs = (chunk & 7) ^ (row & 7);
    GLD16(src + (size_t)row * rstride + kt + cs * 8, dst + chunk * 16);
  }
}

// one K-iteration: optional prefetch into (na,nb), compute on (ca,cb)
__device__ __forceinline__ void gemm_step(
    const bf16* __restrict__ A, const bf16* __restrict__ B, int m0, int n0,
    const char* ca, const char* cb, char* na, char* nb, int ktn, bool pref,
    int tid, int lane, int quad, int wm, int wn, f32x4 (&acc)[4][4]) {
  if (pref) {
    stage_tile(A + (size_t)m0 * 1024, 1024, ktn, na, tid);
    stage_tile(B + (size_t)n0 * 1024, 1024, ktn, nb, tid);
  }
#pragma unroll
  for (int ks = 0; ks < 2; ++ks) {
    bf16x8 af[4], bfr[4];
#pragma unroll
    for (int t = 0; t < 4; ++t) {
      int ra = wm + t * 16 + (lane & 15);
      af[t] = *(const bf16x8*)(ca + ra * 128 + ((ks * 4 + quad) ^ (ra & 7)) * 16);
      int rb = wn + t * 16 + (lane & 15);
      bfr[t] = *(const bf16x8*)(cb + rb * 128 + ((ks * 4 + quad) ^ (rb & 7)) * 16);
    }
#pragma unroll
    for (int mt = 0; mt < 4; ++mt)
#pragma unroll
      for (int nt = 0; nt < 4; ++nt)
        acc[mt][nt] = mfma16(af[mt], bfr[nt], acc[mt][nt]);
  }
  __syncthreads();  // fences LDS reads of (ca,cb); drains prefetch DMA (overlapped)
}

// ---------------- GEMM1: A[8192,1024] @ Bt[3072,1024]^T + bias -> Q,K,Vt (bf16) ----------------
__global__ __launch_bounds__(256, 2) void gemm1_kernel(
    const bf16* __restrict__ A, const bf16* __restrict__ Bt, const float* __restrict__ bias,
    bf16* __restrict__ Qo, bf16* __restrict__ Ko, bf16* __restrict__ Vo) {
  __shared__ __align__(16) char sA[2][128 * 64 * 2];
  __shared__ __align__(16) char sB[2][128 * 64 * 2];
  const int tid = threadIdx.x, lane = tid & 63, quad = lane >> 4;
  const int wave = tid >> 6;
  const int m0 = blockIdx.y * 128, n0 = blockIdx.x * 128;
  const int wm = (wave >> 1) * 64, wn = (wave & 1) * 64;
  f32x4 acc[4][4] = {};

  stage_tile(A + (size_t)m0 * 1024, 1024, 0, sA[0], tid);
  stage_tile(Bt + (size_t)n0 * 1024, 1024, 0, sB[0], tid);
  __syncthreads();
  for (int it = 0; it < 16; it += 2) {
    gemm_step(A, Bt, m0, n0, sA[0], sB[0], sA[1], sB[1], (it + 1) * 64, true,
              tid, lane, quad, wm, wn, acc);
    gemm_step(A, Bt, m0, n0, sA[1], sB[1], sA[0], sB[0], (it + 2) * 64, it + 2 < 16,
              tid, lane, quad, wm, wn, acc);
  }

  const int region = n0 >> 10;  // 0=Q, 1=K, 2=V
#pragma unroll
  for (int nt = 0; nt < 4; ++nt) {
    int n = n0 + wn + nt * 16 + (lane & 15);
    float bv = bias[n];
    int ncol = n & 1023;
    int h = ncol >> 6, d = ncol & 63;
#pragma unroll
    for (int mt = 0; mt < 4; ++mt) {
      int gm = m0 + wm + mt * 16 + quad * 4;
      int bb = gm >> 11, s = gm & 2047;
      if (region == 2) {
        bf16x4 pk;
#pragma unroll
        for (int r = 0; r < 4; ++r) pk[r] = (bf16)(acc[mt][nt][r] + bv);
        *(bf16x4*)(Vo + ((size_t)((bb * 16 + h) * 64 + d)) * 2048 + s) = pk;
      } else {
        bf16* dst = (region == 0) ? Qo : Ko;
        // Q scale: 1/sqrt(64) * log2(e)  (softmax done in base-2)
        float scl = (region == 0) ? 0.18033688f : 1.0f;
#pragma unroll
        for (int r = 0; r < 4; ++r)
          dst[((size_t)((bb * 16 + h) * 2048) + s + r) * 64 + d] =
              (bf16)((acc[mt][nt][r] + bv) * scl);
      }
    }
  }
}

// ---------------- flash attention v4 (unchanged from R4) ----------------
__global__ __launch_bounds__(256, 2) void flash_kernel(
    const bf16* __restrict__ Q, const bf16* __restrict__ K, const bf16* __restrict__ Vt,
    bf16* __restrict__ ctx) {
  const int n = blockIdx.x;
  const int bh = (n & 7) * 8 + (n >> 6);   // XCD swizzle: 8 heads share an XCD L2
  const int qt = (n >> 3) & 7;
  const int b = bh >> 4, h = bh & 15;
  const int tid = threadIdx.x, lane = tid & 63, wave = tid >> 6, quad = lane >> 4;

  __shared__ __align__(16) char sK[2][128 * 64 * 2];  // K dbuf, 2x16KB
  __shared__ __align__(16) char sV[2][64 * 128 * 2];  // V dbuf [d][kv], 2x16KB
  __shared__ __align__(16) char sP[4][64 * 32 * 2];   // per-wave [64q][32kv] 4KB

  const size_t hb = (size_t)bh * 2048 * 64;
  const int q0 = qt * 256;

  // stage Q tile (256 rows) into sK[0]+sK[1] (borrowed), preload qf fragments
#pragma unroll
  for (int i = 0; i < 8; ++i) {
    int chunk = i * 256 + tid;
    int row = chunk >> 3;
    int cs = (chunk & 7) ^ (row & 7);
    char* dst = (i < 4) ? (sK[0] + chunk * 16) : (sK[1] + (chunk - 1024) * 16);
    GLD16(Q + hb + (size_t)(q0 + row) * 64 + cs * 8, dst);
  }
  __syncthreads();
  bf16x8 qf[4][2];  // [j: q 16-tile][ksd: d-half]
#pragma unroll
  for (int j = 0; j < 4; ++j)
#pragma unroll
    for (int ksd = 0; ksd < 2; ++ksd) {
      int row = wave * 64 + j * 16 + (lane & 15);  // 0..255
      const char* src = sK[row >> 7];
      int r128 = row & 127;
      qf[j][ksd] = *(const bf16x8*)(src + r128 * 128 + ((ksd * 4 + quad) ^ (r128 & 7)) * 16);
    }
  __syncthreads();  // all waves done reading Q before buffers are re-staged

  // prologue DMA: K tile 0 -> sK[0], V tile 0 -> sV[0]
#pragma unroll
  for (int i = 0; i < 4; ++i) {
    int chunk = i * 256 + tid;
    int row = chunk >> 3;
    int cs = (chunk & 7) ^ (row & 7);
    GLD16(K + hb + (size_t)row * 64 + cs * 8, sK[0] + chunk * 16);
    int vrow = chunk >> 4;
    int vcs = (chunk & 15) ^ (vrow & 7);
    GLD16(Vt + hb + (size_t)vrow * 2048 + vcs * 8, sV[0] + chunk * 16);
  }
  __syncthreads();

  f32x4 ctxa[4][4] = {};
  float l[4] = {0.f, 0.f, 0.f, 0.f};
  char* pw = sP[wave];

  for (int it = 0; it < 16; ++it) {
    const int kv0 = it * 128;
    // prefetch next K/V tiles into the other buffers; overlaps all compute below
    if (it < 15) {
      char* nk = sK[(it + 1) & 1];
      char* nv = sV[(it + 1) & 1];
#pragma unroll
      for (int i = 0; i < 4; ++i) {
        int chunk = i * 256 + tid;
        int row = chunk >> 3;
        int cs = (chunk & 7) ^ (row & 7);
        GLD16(K + hb + (size_t)(kv0 + 128 + row) * 64 + cs * 8, nk + chunk * 16);
        int vrow = chunk >> 4;
        int vcs = (chunk & 15) ^ (vrow & 7);
        GLD16(Vt + hb + (size_t)vrow * 2048 + kv0 + 128 + vcs * 8, nv + chunk * 16);
      }
    }
    const char* cb = sK[it & 1];
    const char* vb = sV[it & 1];

    // kv quarters of 32
#pragma unroll
    for (int kq = 0; kq < 4; ++kq) {
      // S^T tile: [2 kv-16-tiles][4 q-16-tiles]
      f32x4 st[2][4] = {};
#pragma unroll
      for (int ksd = 0; ksd < 2; ++ksd) {
        bf16x8 kf[2];
#pragma unroll
        for (int ii = 0; ii < 2; ++ii) {
          int row = kq * 32 + ii * 16 + (lane & 15);
          kf[ii] = *(const bf16x8*)(cb + row * 128 + ((ksd * 4 + quad) ^ (row & 7)) * 16);
        }
#pragma unroll
        for (int ii = 0; ii < 2; ++ii)
#pragma unroll
          for (int j = 0; j < 4; ++j)
            st[ii][j] = mfma16(kf[ii], qf[j][ksd], st[ii][j]);
      }
      // p = exp2(s); accumulate row-sum in-lane; write P^T quarter (8B stores)
#pragma unroll
      for (int ii = 0; ii < 2; ++ii)
#pragma unroll
        for (int j = 0; j < 4; ++j) {
          f32x4 p;
#pragma unroll
          for (int r = 0; r < 4; ++r) {
            p[r] = EXP2(st[ii][j][r]);
            l[j] += p[r];
          }
          bf16x4 pk;
#pragma unroll
          for (int r = 0; r < 4; ++r) pk[r] = (bf16)p[r];
          int q = j * 16 + (lane & 15);
          int chunk = ii * 2 + (quad >> 1);
          *(bf16x4*)(pw + q * 64 + ((chunk ^ (q & 3)) * 16) + (quad & 1) * 8) = pk;
        }
      // ctx += P @ V  (quarter: k = 32 kv)
      bf16x8 pf[4], vf[4];
#pragma unroll
      for (int mt = 0; mt < 4; ++mt) {
        int q = mt * 16 + (lane & 15);
        pf[mt] = *(const bf16x8*)(pw + q * 64 + ((quad ^ (q & 3)) * 16));
      }
#pragma unroll
      for (int nd = 0; nd < 4; ++nd) {
        int row = nd * 16 + (lane & 15);
        vf[nd] = *(const bf16x8*)(vb + row * 256 + (((kq * 4 + quad) ^ (row & 7)) * 16));
      }
#pragma unroll
      for (int mt = 0; mt < 4; ++mt)
#pragma unroll
        for (int nd = 0; nd < 4; ++nd)
          ctxa[mt][nd] = mfma16(pf[mt], vf[nd], ctxa[mt][nd]);
    }
    __syncthreads();  // fences buf reads; drains next-tile DMA (fully overlapped)
  }

  // final cross-quad row-sum reduction, then epilogue
#pragma unroll
  for (int j = 0; j < 4; ++j) {
    l[j] += __shfl_xor(l[j], 16);
    l[j] += __shfl_xor(l[j], 32);
  }
#pragma unroll
  for (int mt = 0; mt < 4; ++mt)
#pragma unroll
    for (int r = 0; r < 4; ++r) {
      float lsh = __shfl(l[mt], quad * 4 + r);
      float rl = __builtin_amdgcn_rcpf(lsh);
      int srow = q0 + wave * 64 + mt * 16 + quad * 4 + r;
#pragma unroll
      for (int nd = 0; nd < 4; ++nd) {
        int col = h * 64 + nd * 16 + (lane & 15);
        ctx[((size_t)(b * 2048 + srow)) * 1024 + col] = (bf16)(ctxa[mt][nd][r] * rl);
      }
    }
}

// ---------------- GEMM2: ctx[8192,1024] @ Bt[1024,1024]^T + b_out -> f32 out ----------------
__global__ __launch_bounds__(256, 2) void gemm2_kernel(
    const bf16* __restrict__ A, const bf16* __restrict__ Bt, const float* __restrict__ bias,
    float* __restrict__ Out) {
  __shared__ __align__(16) char sA[2][128 * 64 * 2];
  __shared__ __align__(16) char sB[2][128 * 64 * 2];
  const int tid = threadIdx.x, lane = tid & 63, quad = lane >> 4;
  const int wave = tid >> 6;
  const int m0 = blockIdx.y * 128, n0 = blockIdx.x * 128;
  const int wm = (wave >> 1) * 64, wn = (wave & 1) * 64;
  f32x4 acc[4][4] = {};

  stage_tile(A + (size_t)m0 * 1024, 1024, 0, sA[0], tid);
  stage_tile(Bt + (size_t)n0 * 1024, 1024, 0, sB[0], tid);
  __syncthreads();
  for (int it = 0; it < 16; it += 2) {
    gemm_step(A, Bt, m0, n0, sA[0], sB[0], sA[1], sB[1], (it + 1) * 64, true,
              tid, lane, quad, wm, wn, acc);
    gemm_step(A, Bt, m0, n0, sA[1], sB[1], sA[0], sB[0], (it + 2) * 64, it + 2 < 16,
              tid, lane, quad, wm, wn, acc);
  }

#pragma unroll
  for (int nt = 0; nt < 4; ++nt) {
    int n = n0 + wn + nt * 16 + (lane & 15);
    float bv = bias[n];
#pragma unroll
    for (int mt = 0; mt < 4; ++mt) {
      int gm = m0 + wm + mt * 16 + quad * 4;
#pragma unroll
      for (int r = 0; r < 4; ++r)
        Out[(size_t)(gm + r) * 1024 + n] = acc[mt][nt][r] + bv;
    }
  }
}

extern "C" void kernel_launch(void* const* d_in, const int* in_sizes, int n_in,
                              void* d_out, int out_size, void* d_ws, size_t ws_size,
                              hipStream_t stream) {
  const float* qkv   = (const float*)d_in[0];
  const float* W_in  = (const float*)d_in[1];
  const float* b_in  = (const float*)d_in[2];
  const float* W_out = (const float*)d_in[3];
  const float* b_out = (const float*)d_in[4];
  float* out = (float*)d_out;

  bf16* Xb    = (bf16*)d_ws;
  bf16* WtIn  = Xb + 8388608;
  bf16* WtOut = WtIn + 3145728;
  bf16* Qb    = WtOut + 1048576;
  bf16* Kb    = Qb + 8388608;
  bf16* Vtb   = Kb + 8388608;
  bf16* Ctx   = Xb;

  cast_kernel<<<8192, 256, 0, stream>>>(qkv, Xb, 8388608);
  transpose_cast_kernel<<<dim3(96, 32), dim3(32, 8), 0, stream>>>(W_in, WtIn, 1024, 3072);
  transpose_cast_kernel<<<dim3(32, 32), dim3(32, 8), 0, stream>>>(W_out, WtOut, 1024, 1024);
  gemm1_kernel<<<dim3(24, 64), 256, 0, stream>>>(Xb, WtIn, b_in, Qb, Kb, Vtb);
  flash_kernel<<<512, 256, 0, stream>>>(Qb, Kb, Vtb, Ctx);
  gemm2_kernel<<<dim3(8, 64), 256, 0, stream>>>(Ctx, WtOut, b_out, out);
}

// Round 6
// 251.301 us; speedup vs baseline: 1.9726x; 1.0512x over previous
//
#include <hip/hip_runtime.h>

// Fused MHA: qkv[4,2048,1024] f32 -> out f32, all GEMMs in bf16 MFMA.
// R6: XCD-partitioned rasterization for gemm1/gemm2 — id&7 selects XCD slab
// (8 m-tiles, A slab L2-resident), n streamed (R5 lesson: GEMMs were
// L3-staging-bound, ~768MB refetch; dbuf was neutral). prep kernel merges
// cast + both weight transposes. Flash v4 unchanged (86us).

typedef __bf16 bf16;
typedef __bf16 bf16x4 __attribute__((ext_vector_type(4)));
typedef __bf16 bf16x8 __attribute__((ext_vector_type(8)));
typedef float f32x4 __attribute__((ext_vector_type(4)));

typedef const __attribute__((address_space(1))) void* gas1p;
typedef __attribute__((address_space(3))) void* las3p;
#define GLD16(g, l) __builtin_amdgcn_global_load_lds((gas1p)(g), (las3p)(l), 16, 0, 0)

#if __has_builtin(__builtin_amdgcn_exp2f)
#define EXP2(x) __builtin_amdgcn_exp2f(x)
#else
#define EXP2(x) exp2f(x)
#endif

__device__ __forceinline__ f32x4 mfma16(bf16x8 a, bf16x8 b, f32x4 c) {
  return __builtin_amdgcn_mfma_f32_16x16x32_bf16(a, b, c, 0, 0, 0);
}

// ---------------- prep: cast qkv -> bf16, transpose+cast W_in, W_out ----------------
// blocks 0..8191: cast; 8192..11263: W_in transpose (96x32 tiles); 11264..12287: W_out (32x32)
__global__ void prep_kernel(const float* __restrict__ qkv, bf16* __restrict__ Xb,
                            const float* __restrict__ W_in, bf16* __restrict__ WtIn,
                            const float* __restrict__ W_out, bf16* __restrict__ WtOut) {
  __shared__ float tile[32][33];
  int blk = blockIdx.x, tid = threadIdx.x;
  if (blk < 8192) {
    int i = (blk * 256 + tid) * 4;
    float4 v = *(const float4*)(qkv + i);
    bf16x4 o;
    o[0] = (bf16)v.x; o[1] = (bf16)v.y; o[2] = (bf16)v.z; o[3] = (bf16)v.w;
    *(bf16x4*)(Xb + i) = o;
    return;
  }
  const float* in; bf16* out; int R, C, c0, r0;
  if (blk < 11264) {
    int t = blk - 8192; in = W_in; out = WtIn; R = 1024; C = 3072;
    c0 = (t % 96) * 32; r0 = (t / 96) * 32;
  } else {
    int t = blk - 11264; in = W_out; out = WtOut; R = 1024; C = 1024;
    c0 = (t % 32) * 32; r0 = (t / 32) * 32;
  }
  int tx = tid & 31, ty = tid >> 5;
#pragma unroll
  for (int i = 0; i < 4; ++i)
    tile[ty + i * 8][tx] = in[(size_t)(r0 + ty + i * 8) * C + c0 + tx];
  __syncthreads();
#pragma unroll
  for (int i = 0; i < 4; ++i)
    out[(size_t)(c0 + ty + i * 8) * R + r0 + tx] = (bf16)tile[tx][ty + i * 8];
}

// ======== shared dbuf-GEMM machinery: 128x128 tile, BK=64, K=1024 ========
__device__ __forceinline__ void stage_tile(const bf16* __restrict__ src, size_t rstride,
                                           int kt, char* dst, int tid) {
#pragma unroll
  for (int i = 0; i < 4; ++i) {
    int chunk = i * 256 + tid;
    int row = chunk >> 3;
    int cs = (chunk & 7) ^ (row & 7);
    GLD16(src + (size_t)row * rstride + kt + cs * 8, dst + chunk * 16);
  }
}

__device__ __forceinline__ void gemm_step(
    const bf16* __restrict__ A, const bf16* __restrict__ B, int m0, int n0,
    const char* ca, const char* cb, char* na, char* nb, int ktn, bool pref,
    int tid, int lane, int quad, int wm, int wn, f32x4 (&acc)[4][4]) {
  if (pref) {
    stage_tile(A + (size_t)m0 * 1024, 1024, ktn, na, tid);
    stage_tile(B + (size_t)n0 * 1024, 1024, ktn, nb, tid);
  }
#pragma unroll
  for (int ks = 0; ks < 2; ++ks) {
    bf16x8 af[4], bfr[4];
#pragma unroll
    for (int t = 0; t < 4; ++t) {
      int ra = wm + t * 16 + (lane & 15);
      af[t] = *(const bf16x8*)(ca + ra * 128 + ((ks * 4 + quad) ^ (ra & 7)) * 16);
      int rb = wn + t * 16 + (lane & 15);
      bfr[t] = *(const bf16x8*)(cb + rb * 128 + ((ks * 4 + quad) ^ (rb & 7)) * 16);
    }
#pragma unroll
    for (int mt = 0; mt < 4; ++mt)
#pragma unroll
      for (int nt = 0; nt < 4; ++nt)
        acc[mt][nt] = mfma16(af[mt], bfr[nt], acc[mt][nt]);
  }
  __syncthreads();
}

// ---------------- GEMM1: A[8192,1024] @ Bt[3072,1024]^T + bias -> Q,K,Vt (bf16) ----------------
// 1536 blocks flat. XCD partition: xcd=id&7 owns m-tiles xcd*8..xcd*8+7 (A slab
// 2MB L2-resident); n streamed, 8 m-tiles back-to-back per n (B panel reuse).
__global__ __launch_bounds__(256, 2) void gemm1_kernel(
    const bf16* __restrict__ A, const bf16* __restrict__ Bt, const float* __restrict__ bias,
    bf16* __restrict__ Qo, bf16* __restrict__ Ko, bf16* __restrict__ Vo) {
  __shared__ __align__(16) char sA[2][128 * 64 * 2];
  __shared__ __align__(16) char sB[2][128 * 64 * 2];
  const int tid = threadIdx.x, lane = tid & 63, quad = lane >> 4;
  const int wave = tid >> 6;
  const int id = blockIdx.x, xcd = id & 7, local = id >> 3;
  const int m0 = (xcd * 8 + (local & 7)) * 128, n0 = (local >> 3) * 128;
  const int wm = (wave >> 1) * 64, wn = (wave & 1) * 64;
  f32x4 acc[4][4] = {};

  stage_tile(A + (size_t)m0 * 1024, 1024, 0, sA[0], tid);
  stage_tile(Bt + (size_t)n0 * 1024, 1024, 0, sB[0], tid);
  __syncthreads();
  for (int it = 0; it < 16; it += 2) {
    gemm_step(A, Bt, m0, n0, sA[0], sB[0], sA[1], sB[1], (it + 1) * 64, true,
              tid, lane, quad, wm, wn, acc);
    gemm_step(A, Bt, m0, n0, sA[1], sB[1], sA[0], sB[0], (it + 2) * 64, it + 2 < 16,
              tid, lane, quad, wm, wn, acc);
  }

  const int region = n0 >> 10;  // 0=Q, 1=K, 2=V
#pragma unroll
  for (int nt = 0; nt < 4; ++nt) {
    int n = n0 + wn + nt * 16 + (lane & 15);
    float bv = bias[n];
    int ncol = n & 1023;
    int h = ncol >> 6, d = ncol & 63;
#pragma unroll
    for (int mt = 0; mt < 4; ++mt) {
      int gm = m0 + wm + mt * 16 + quad * 4;
      int bb = gm >> 11, s = gm & 2047;
      if (region == 2) {
        bf16x4 pk;
#pragma unroll
        for (int r = 0; r < 4; ++r) pk[r] = (bf16)(acc[mt][nt][r] + bv);
        *(bf16x4*)(Vo + ((size_t)((bb * 16 + h) * 64 + d)) * 2048 + s) = pk;
      } else {
        bf16* dst = (region == 0) ? Qo : Ko;
        // Q scale: 1/sqrt(64) * log2(e)  (softmax done in base-2)
        float scl = (region == 0) ? 0.18033688f : 1.0f;
#pragma unroll
        for (int r = 0; r < 4; ++r)
          dst[((size_t)((bb * 16 + h) * 2048) + s + r) * 64 + d] =
              (bf16)((acc[mt][nt][r] + bv) * scl);
      }
    }
  }
}

// ---------------- flash attention v4 (unchanged) ----------------
__global__ __launch_bounds__(256, 2) void flash_kernel(
    const bf16* __restrict__ Q, const bf16* __restrict__ K, const bf16* __restrict__ Vt,
    bf16* __restrict__ ctx) {
  const int n = blockIdx.x;
  const int bh = (n & 7) * 8 + (n >> 6);   // XCD swizzle: 8 heads share an XCD L2
  const int qt = (n >> 3) & 7;
  const int b = bh >> 4, h = bh & 15;
  const int tid = threadIdx.x, lane = tid & 63, wave = tid >> 6, quad = lane >> 4;

  __shared__ __align__(16) char sK[2][128 * 64 * 2];  // K dbuf, 2x16KB
  __shared__ __align__(16) char sV[2][64 * 128 * 2];  // V dbuf [d][kv], 2x16KB
  __shared__ __align__(16) char sP[4][64 * 32 * 2];   // per-wave [64q][32kv] 4KB

  const size_t hb = (size_t)bh * 2048 * 64;
  const int q0 = qt * 256;

#pragma unroll
  for (int i = 0; i < 8; ++i) {
    int chunk = i * 256 + tid;
    int row = chunk >> 3;
    int cs = (chunk & 7) ^ (row & 7);
    char* dst = (i < 4) ? (sK[0] + chunk * 16) : (sK[1] + (chunk - 1024) * 16);
    GLD16(Q + hb + (size_t)(q0 + row) * 64 + cs * 8, dst);
  }
  __syncthreads();
  bf16x8 qf[4][2];
#pragma unroll
  for (int j = 0; j < 4; ++j)
#pragma unroll
    for (int ksd = 0; ksd < 2; ++ksd) {
      int row = wave * 64 + j * 16 + (lane & 15);
      const char* src = sK[row >> 7];
      int r128 = row & 127;
      qf[j][ksd] = *(const bf16x8*)(src + r128 * 128 + ((ksd * 4 + quad) ^ (r128 & 7)) * 16);
    }
  __syncthreads();

#pragma unroll
  for (int i = 0; i < 4; ++i) {
    int chunk = i * 256 + tid;
    int row = chunk >> 3;
    int cs = (chunk & 7) ^ (row & 7);
    GLD16(K + hb + (size_t)row * 64 + cs * 8, sK[0] + chunk * 16);
    int vrow = chunk >> 4;
    int vcs = (chunk & 15) ^ (vrow & 7);
    GLD16(Vt + hb + (size_t)vrow * 2048 + vcs * 8, sV[0] + chunk * 16);
  }
  __syncthreads();

  f32x4 ctxa[4][4] = {};
  float l[4] = {0.f, 0.f, 0.f, 0.f};
  char* pw = sP[wave];

  for (int it = 0; it < 16; ++it) {
    const int kv0 = it * 128;
    if (it < 15) {
      char* nk = sK[(it + 1) & 1];
      char* nv = sV[(it + 1) & 1];
#pragma unroll
      for (int i = 0; i < 4; ++i) {
        int chunk = i * 256 + tid;
        int row = chunk >> 3;
        int cs = (chunk & 7) ^ (row & 7);
        GLD16(K + hb + (size_t)(kv0 + 128 + row) * 64 + cs * 8, nk + chunk * 16);
        int vrow = chunk >> 4;
        int vcs = (chunk & 15) ^ (vrow & 7);
        GLD16(Vt + hb + (size_t)vrow * 2048 + kv0 + 128 + vcs * 8, nv + chunk * 16);
      }
    }
    const char* cb = sK[it & 1];
    const char* vb = sV[it & 1];

#pragma unroll
    for (int kq = 0; kq < 4; ++kq) {
      f32x4 st[2][4] = {};
#pragma unroll
      for (int ksd = 0; ksd < 2; ++ksd) {
        bf16x8 kf[2];
#pragma unroll
        for (int ii = 0; ii < 2; ++ii) {
          int row = kq * 32 + ii * 16 + (lane & 15);
          kf[ii] = *(const bf16x8*)(cb + row * 128 + ((ksd * 4 + quad) ^ (row & 7)) * 16);
        }
#pragma unroll
        for (int ii = 0; ii < 2; ++ii)
#pragma unroll
          for (int j = 0; j < 4; ++j)
            st[ii][j] = mfma16(kf[ii], qf[j][ksd], st[ii][j]);
      }
#pragma unroll
      for (int ii = 0; ii < 2; ++ii)
#pragma unroll
        for (int j = 0; j < 4; ++j) {
          f32x4 p;
#pragma unroll
          for (int r = 0; r < 4; ++r) {
            p[r] = EXP2(st[ii][j][r]);
            l[j] += p[r];
          }
          bf16x4 pk;
#pragma unroll
          for (int r = 0; r < 4; ++r) pk[r] = (bf16)p[r];
          int q = j * 16 + (lane & 15);
          int chunk = ii * 2 + (quad >> 1);
          *(bf16x4*)(pw + q * 64 + ((chunk ^ (q & 3)) * 16) + (quad & 1) * 8) = pk;
        }
      bf16x8 pf[4], vf[4];
#pragma unroll
      for (int mt = 0; mt < 4; ++mt) {
        int q = mt * 16 + (lane & 15);
        pf[mt] = *(const bf16x8*)(pw + q * 64 + ((quad ^ (q & 3)) * 16));
      }
#pragma unroll
      for (int nd = 0; nd < 4; ++nd) {
        int row = nd * 16 + (lane & 15);
        vf[nd] = *(const bf16x8*)(vb + row * 256 + (((kq * 4 + quad) ^ (row & 7)) * 16));
      }
#pragma unroll
      for (int mt = 0; mt < 4; ++mt)
#pragma unroll
        for (int nd = 0; nd < 4; ++nd)
          ctxa[mt][nd] = mfma16(pf[mt], vf[nd], ctxa[mt][nd]);
    }
    __syncthreads();
  }

#pragma unroll
  for (int j = 0; j < 4; ++j) {
    l[j] += __shfl_xor(l[j], 16);
    l[j] += __shfl_xor(l[j], 32);
  }
#pragma unroll
  for (int mt = 0; mt < 4; ++mt)
#pragma unroll
    for (int r = 0; r < 4; ++r) {
      float lsh = __shfl(l[mt], quad * 4 + r);
      float rl = __builtin_amdgcn_rcpf(lsh);
      int srow = q0 + wave * 64 + mt * 16 + quad * 4 + r;
#pragma unroll
      for (int nd = 0; nd < 4; ++nd) {
        int col = h * 64 + nd * 16 + (lane & 15);
        ctx[((size_t)(b * 2048 + srow)) * 1024 + col] = (bf16)(ctxa[mt][nd][r] * rl);
      }
    }
}

// ---------------- GEMM2: ctx[8192,1024] @ Bt[1024,1024]^T + b_out -> f32 out ----------------
// 512 blocks flat. XCD partition: xcd=id&7 owns m-tiles xcd*8..+7; per-XCD
// footprint A 2MB + B 2MB = 4MB (fits L2).
__global__ __launch_bounds__(256, 2) void gemm2_kernel(
    const bf16* __restrict__ A, const bf16* __restrict__ Bt, const float* __restrict__ bias,
    float* __restrict__ Out) {
  __shared__ __align__(16) char sA[2][128 * 64 * 2];
  __shared__ __align__(16) char sB[2][128 * 64 * 2];
  const int tid = threadIdx.x, lane = tid & 63, quad = lane >> 4;
  const int wave = tid >> 6;
  const int id = blockIdx.x, xcd = id & 7, local = id >> 3;
  const int m0 = (xcd * 8 + (local & 7)) * 128, n0 = (local >> 3) * 128;
  const int wm = (wave >> 1) * 64, wn = (wave & 1) * 64;
  f32x4 acc[4][4] = {};

  stage_tile(A + (size_t)m0 * 1024, 1024, 0, sA[0], tid);
  stage_tile(Bt + (size_t)n0 * 1024, 1024, 0, sB[0], tid);
  __syncthreads();
  for (int it = 0; it < 16; it += 2) {
    gemm_step(A, Bt, m0, n0, sA[0], sB[0], sA[1], sB[1], (it + 1) * 64, true,
              tid, lane, quad, wm, wn, acc);
    gemm_step(A, Bt, m0, n0, sA[1], sB[1], sA[0], sB[0], (it + 2) * 64, it + 2 < 16,
              tid, lane, quad, wm, wn, acc);
  }

#pragma unroll
  for (int nt = 0; nt < 4; ++nt) {
    int n = n0 + wn + nt * 16 + (lane & 15);
    float bv = bias[n];
#pragma unroll
    for (int mt = 0; mt < 4; ++mt) {
      int gm = m0 + wm + mt * 16 + quad * 4;
#pragma unroll
      for (int r = 0; r < 4; ++r)
        Out[(size_t)(gm + r) * 1024 + n] = acc[mt][nt][r] + bv;
    }
  }
}

extern "C" void kernel_launch(void* const* d_in, const int* in_sizes, int n_in,
                              void* d_out, int out_size, void* d_ws, size_t ws_size,
                              hipStream_t stream) {
  const float* qkv   = (const float*)d_in[0];
  const float* W_in  = (const float*)d_in[1];
  const float* b_in  = (const float*)d_in[2];
  const float* W_out = (const float*)d_in[3];
  const float* b_out = (const float*)d_in[4];
  float* out = (float*)d_out;

  bf16* Xb    = (bf16*)d_ws;
  bf16* WtIn  = Xb + 8388608;
  bf16* WtOut = WtIn + 3145728;
  bf16* Qb    = WtOut + 1048576;
  bf16* Kb    = Qb + 8388608;
  bf16* Vtb   = Kb + 8388608;
  bf16* Ctx   = Xb;

  prep_kernel<<<12288, 256, 0, stream>>>(qkv, Xb, W_in, WtIn, W_out, WtOut);
  gemm1_kernel<<<1536, 256, 0, stream>>>(Xb, WtIn, b_in, Qb, Kb, Vtb);
  flash_kernel<<<512, 256, 0, stream>>>(Qb, Kb, Vtb, Ctx);
  gemm2_kernel<<<512, 256, 0, stream>>>(Ctx, WtOut, b_out, out);
}